// Round 1
// baseline (714.197 us; speedup 1.0000x reference)
//
#include <hip/hip_runtime.h>

#define N_ROWS 32768
#define DIM    256
#define KCODES 2048

#define TM 64   // rows per block tile
#define TK 64   // codes per block tile
#define TD 32   // depth chunk

// ---------------- kernel A: codebook squared norms (+ zero the loss cell) ---------
__global__ void cnorm_kernel(const float* __restrict__ cb, float* __restrict__ cnorm,
                             float* __restrict__ loss) {
    const int code = blockIdx.x;
    const int t = threadIdx.x;                 // 256 threads
    if (code == 0 && t == 0) *loss = 0.0f;     // ordered before gather_loss launch
    float v = cb[code * DIM + t];
    float s = v * v;
    #pragma unroll
    for (int o = 32; o > 0; o >>= 1) s += __shfl_down(s, o, 64);
    __shared__ float red[4];
    if ((t & 63) == 0) red[t >> 6] = s;
    __syncthreads();
    if (t == 0) cnorm[code] = red[0] + red[1] + red[2] + red[3];
}

// ---------------- kernel B: argmin over codes ------------------------------------
// dist'(n,k) = ||c_k||^2 - 2 * x_n . c_k   (row norm dropped — constant per row)
__global__ __launch_bounds__(256) void argmin_kernel(
        const float* __restrict__ x, const float* __restrict__ cb,
        const float* __restrict__ cnorm, int* __restrict__ inds) {
    __shared__ float xs[TM][TD + 4];    // row-major, stride 36 floats (16B aligned, 2-way banks)
    __shared__ float cst[TD][TK];       // transposed: [d][code], stride 64
    __shared__ float red_v[TM][16];
    __shared__ int   red_i[TM][16];

    const int t   = threadIdx.x;
    const int tc  = t & 15;    // code group 0..15  (4 codes each)
    const int tr  = t >> 4;    // row  group 0..15  (4 rows each)
    const int row0 = blockIdx.x * TM;

    // staging index maps
    const int xr = t >> 3;           // 0..31 (rows xr, xr+32)
    const int xc = (t & 7) * 4;      // d offset 0..28
    const int ck = t & 31;           // 0..31 (codes ck, ck+32)
    const int cc = (t >> 5) * 4;     // d offset 0..28

    float minv[4];
    int   mini[4];
    #pragma unroll
    for (int i = 0; i < 4; i++) { minv[i] = 3.4e38f; mini[i] = 0; }

    for (int k0 = 0; k0 < KCODES; k0 += TK) {
        float acc[4][4];
        #pragma unroll
        for (int i = 0; i < 4; i++)
            #pragma unroll
            for (int j = 0; j < 4; j++) acc[i][j] = 0.0f;

        for (int d0 = 0; d0 < DIM; d0 += TD) {
            __syncthreads();
            // stage x tile [64 rows x 32 d]
            {
                float4 v0 = *(const float4*)&x[(size_t)(row0 + xr) * DIM + d0 + xc];
                float4 v1 = *(const float4*)&x[(size_t)(row0 + xr + 32) * DIM + d0 + xc];
                *(float4*)&xs[xr][xc]      = v0;
                *(float4*)&xs[xr + 32][xc] = v1;
            }
            // stage code tile transposed [32 d x 64 codes]
            {
                float4 v0 = *(const float4*)&cb[(size_t)(k0 + ck) * DIM + d0 + cc];
                float4 v1 = *(const float4*)&cb[(size_t)(k0 + ck + 32) * DIM + d0 + cc];
                cst[cc + 0][ck] = v0.x; cst[cc + 1][ck] = v0.y;
                cst[cc + 2][ck] = v0.z; cst[cc + 3][ck] = v0.w;
                cst[cc + 0][ck + 32] = v1.x; cst[cc + 1][ck + 32] = v1.y;
                cst[cc + 2][ck + 32] = v1.z; cst[cc + 3][ck + 32] = v1.w;
            }
            __syncthreads();

            #pragma unroll
            for (int dd = 0; dd < TD; dd += 4) {
                float4 a0 = *(const float4*)&xs[tr * 4 + 0][dd];
                float4 a1 = *(const float4*)&xs[tr * 4 + 1][dd];
                float4 a2 = *(const float4*)&xs[tr * 4 + 2][dd];
                float4 a3 = *(const float4*)&xs[tr * 4 + 3][dd];
                float4 b0 = *(const float4*)&cst[dd + 0][tc * 4];
                float4 b1 = *(const float4*)&cst[dd + 1][tc * 4];
                float4 b2 = *(const float4*)&cst[dd + 2][tc * 4];
                float4 b3 = *(const float4*)&cst[dd + 3][tc * 4];
                #define STEP(ai, r) \
                    acc[r][0] += ai.x*b0.x + ai.y*b1.x + ai.z*b2.x + ai.w*b3.x; \
                    acc[r][1] += ai.x*b0.y + ai.y*b1.y + ai.z*b2.y + ai.w*b3.y; \
                    acc[r][2] += ai.x*b0.z + ai.y*b1.z + ai.z*b2.z + ai.w*b3.z; \
                    acc[r][3] += ai.x*b0.w + ai.y*b1.w + ai.z*b2.w + ai.w*b3.w;
                STEP(a0, 0) STEP(a1, 1) STEP(a2, 2) STEP(a3, 3)
                #undef STEP
            }
        }

        // fold this K-tile into the running min
        #pragma unroll
        for (int j = 0; j < 4; j++) {
            const int code = k0 + tc * 4 + j;
            const float cn = cnorm[code];
            #pragma unroll
            for (int i = 0; i < 4; i++) {
                float dist = cn - 2.0f * acc[i][j];
                if (dist < minv[i] || (dist == minv[i] && code < mini[i])) {
                    minv[i] = dist; mini[i] = code;
                }
            }
        }
    }

    // cross-thread reduction: 16 candidates per row
    #pragma unroll
    for (int i = 0; i < 4; i++) {
        red_v[tr * 4 + i][tc] = minv[i];
        red_i[tr * 4 + i][tc] = mini[i];
    }
    __syncthreads();
    if (t < TM) {
        float bv = red_v[t][0];
        int   bi = red_i[t][0];
        #pragma unroll
        for (int q = 1; q < 16; q++) {
            float v = red_v[t][q]; int ii = red_i[t][q];
            if (v < bv || (v == bv && ii < bi)) { bv = v; bi = ii; }
        }
        inds[row0 + t] = bi;
    }
}

// ---------------- kernel C: gather + loss ----------------------------------------
__global__ void gather_loss_kernel(const float* __restrict__ x, const float* __restrict__ cb,
                                   const int* __restrict__ inds, float* __restrict__ out,
                                   float* __restrict__ loss) {
    const int t = threadIdx.x;    // 256 threads cover D
    float lsum = 0.0f;
    #pragma unroll
    for (int r = 0; r < 16; r++) {
        const int row  = blockIdx.x * 16 + r;
        const int code = inds[row];
        const float c  = cb[(size_t)code * DIM + t];
        const float xv = x[(size_t)row * DIM + t];
        out[(size_t)row * DIM + t] = c;
        const float diff = xv - c;
        lsum += diff * diff;
    }
    #pragma unroll
    for (int o = 32; o > 0; o >>= 1) lsum += __shfl_down(lsum, o, 64);
    __shared__ float red[4];
    if ((t & 63) == 0) red[t >> 6] = lsum;
    __syncthreads();
    if (t == 0) {
        const float scale = 1.25f / (float)(N_ROWS * DIM);  // (beta + 1) / (N*D)
        atomicAdd(loss, (red[0] + red[1] + red[2] + red[3]) * scale);
    }
}

extern "C" void kernel_launch(void* const* d_in, const int* in_sizes, int n_in,
                              void* d_out, int out_size, void* d_ws, size_t ws_size,
                              hipStream_t stream) {
    const float* x  = (const float*)d_in[0];
    const float* cb = (const float*)d_in[1];
    float* out   = (float*)d_out;
    float* loss  = out + (size_t)N_ROWS * DIM;   // last element of d_out
    float* cnorm = (float*)d_ws;
    int*   inds  = (int*)((char*)d_ws + KCODES * sizeof(float));

    cnorm_kernel<<<KCODES, 256, 0, stream>>>(cb, cnorm, loss);
    argmin_kernel<<<N_ROWS / TM, 256, 0, stream>>>(x, cb, cnorm, inds);
    gather_loss_kernel<<<N_ROWS / 16, 256, 0, stream>>>(x, cb, inds, out, loss);
}

// Round 2
// 175.256 us; speedup vs baseline: 4.0752x; 4.0752x over previous
//
#include <hip/hip_runtime.h>

#define N_ROWS 32768
#define DIM    256
#define KCODES 2048

typedef unsigned short ushort_t;
typedef __attribute__((ext_vector_type(8)))  short bf16x8;
typedef __attribute__((ext_vector_type(16))) float f32x16;

__device__ __forceinline__ unsigned short f2bf(float f) {
    union { float f; unsigned int u; } v; v.f = f;
    unsigned int r = v.u + 0x7FFFu + ((v.u >> 16) & 1u);   // RNE (inputs finite)
    return (unsigned short)(r >> 16);
}

__device__ __forceinline__ void gl16(const void* g, void* l) {
    __builtin_amdgcn_global_load_lds(
        (const __attribute__((address_space(1))) unsigned int*)g,
        (__attribute__((address_space(3))) unsigned int*)l, 16, 0, 0);
}

// ---------------- prologue 1: x fp32 -> bf16 (into d_out scratch region) --------
__global__ void prep_x(const float* __restrict__ x, ushort_t* __restrict__ xb) {
    const int i = (blockIdx.x * 256 + threadIdx.x) * 8;
    float4 v0 = *(const float4*)(x + i);
    float4 v1 = *(const float4*)(x + i + 4);
    uint4 o;
    o.x = (unsigned)f2bf(v0.x) | ((unsigned)f2bf(v0.y) << 16);
    o.y = (unsigned)f2bf(v0.z) | ((unsigned)f2bf(v0.w) << 16);
    o.z = (unsigned)f2bf(v1.x) | ((unsigned)f2bf(v1.y) << 16);
    o.w = (unsigned)f2bf(v1.z) | ((unsigned)f2bf(v1.w) << 16);
    *(uint4*)(xb + i) = o;
}

// ---------------- prologue 2: cb -> bf16, halfcn = 0.5*||c||^2, zero loss -------
__global__ void prep_cb(const float* __restrict__ cb, ushort_t* __restrict__ cbb,
                        float* __restrict__ halfcn, float* __restrict__ loss) {
    const int code = blockIdx.x;
    const int t = threadIdx.x;               // 256 threads = D
    if (code == 0 && t == 0) *loss = 0.0f;
    float v = cb[code * DIM + t];
    cbb[code * DIM + t] = f2bf(v);
    float s = v * v;
    #pragma unroll
    for (int o = 32; o > 0; o >>= 1) s += __shfl_down(s, o, 64);
    __shared__ float red[4];
    if ((t & 63) == 0) red[t >> 6] = s;
    __syncthreads();
    if (t == 0) halfcn[code] = 0.5f * (red[0] + red[1] + red[2] + red[3]);
}

// ---------------- main: bf16 MFMA distance GEMM fused with argmax(score) --------
// score(n,k) = x_n . c_k - 0.5*||c_k||^2  (argmax score == argmin dist)
// acc initialized to -halfcn; fold packs 11-bit code id into low mantissa bits.
__global__ __launch_bounds__(256, 2) void argmin_mfma(
        const ushort_t* __restrict__ xb, const ushort_t* __restrict__ cbb,
        const float* __restrict__ halfcn, int* __restrict__ inds) {
    __shared__ char As[2][4096];     // 64 rows x 32 k bf16, swizzled 16B pieces
    __shared__ char Bs[2][16384];    // 256 codes x 32 k bf16, swizzled
    __shared__ float red[64][4];

    const int t    = threadIdx.x;
    const int lane = t & 63;
    const int w    = t >> 6;         // wave 0..3 -> code quadrant
    const int l32  = lane & 31;
    const int h    = lane >> 5;
    const int row0 = blockIdx.x * 64;

    // ---- staging source addresses (16B per lane, swizzled k-piece) ----
    const int a_r = w * 16 + (lane >> 2);                 // local row 0..63
    const int a_j = (lane & 3) ^ ((a_r >> 1) & 3);
    const ushort_t* a_src = xb + (size_t)(row0 + a_r) * DIM + a_j * 8;

    int b_j[4];
    const ushort_t* b_src[4];
    #pragma unroll
    for (int m = 0; m < 4; m++) {
        const int c = (m * 4 + w) * 16 + (lane >> 2);     // local code 0..255
        b_j[m] = (lane & 3) ^ ((c >> 1) & 3);
        b_src[m] = cbb + (size_t)c * DIM + b_j[m] * 8;
    }

    // ---- preload bias 0.5||c||^2 for this wave's codes across all 8 tiles ----
    float hcv[8][2];
    #pragma unroll
    for (int tile = 0; tile < 8; tile++)
        #pragma unroll
        for (int ct = 0; ct < 2; ct++)
            hcv[tile][ct] = halfcn[tile * 256 + w * 64 + ct * 32 + l32];

    f32x16 acc[2][2];
    #pragma unroll
    for (int rt = 0; rt < 2; rt++)
        #pragma unroll
        for (int ct = 0; ct < 2; ct++)
            #pragma unroll
            for (int r = 0; r < 16; r++) acc[rt][ct][r] = -hcv[0][ct];

    float mp[2][16];
    #pragma unroll
    for (int rt = 0; rt < 2; rt++)
        #pragma unroll
        for (int r = 0; r < 16; r++) mp[rt][r] = -3.0e38f;

    const int fa  = (l32 >> 1) & 3;
    const int pk0 = ((0 + h) ^ fa) * 16;                  // kstep 0 piece offset
    const int pk1 = ((2 + h) ^ fa) * 16;                  // kstep 1 piece offset

    // ---- stage chunk 0 into buffer 0 ----
    gl16(a_src, As[0] + w * 1024);
    #pragma unroll
    for (int m = 0; m < 4; m++) gl16(b_src[m], Bs[0] + (m * 4 + w) * 1024);

    int cur = 0;
    for (int c = 0; c < 64; ++c) {
        __syncthreads();   // drains vmcnt: buf[cur] staged; prev reads of buf[cur^1] done
        const int ct8 = c >> 3;
        const int ki  = c & 7;
        if (c < 63) {
            const int cn = c + 1, ctn = cn >> 3, kin = cn & 7;
            const int nb = cur ^ 1;
            gl16(a_src + kin * 32, As[nb] + w * 1024);
            const size_t goff = (size_t)ctn * (256 * DIM) + kin * 32;
            #pragma unroll
            for (int m = 0; m < 4; m++)
                gl16(b_src[m] + goff, Bs[nb] + (m * 4 + w) * 1024);
        }

        // ---- LDS -> fragments ----
        const char* ab = As[cur];
        const char* bb = Bs[cur];
        bf16x8 af[2][2], bfr[2][2];
        #pragma unroll
        for (int rt = 0; rt < 2; rt++) {
            af[rt][0] = *(const bf16x8*)(ab + (rt * 32 + l32) * 64 + pk0);
            af[rt][1] = *(const bf16x8*)(ab + (rt * 32 + l32) * 64 + pk1);
        }
        #pragma unroll
        for (int ct = 0; ct < 2; ct++) {
            const int cl = w * 64 + ct * 32 + l32;
            bfr[ct][0] = *(const bf16x8*)(bb + cl * 64 + pk0);
            bfr[ct][1] = *(const bf16x8*)(bb + cl * 64 + pk1);
        }

        #pragma unroll
        for (int ks = 0; ks < 2; ks++)
            #pragma unroll
            for (int rt = 0; rt < 2; rt++)
                #pragma unroll
                for (int ct = 0; ct < 2; ct++)
                    acc[rt][ct] = __builtin_amdgcn_mfma_f32_32x32x16_bf16(
                        af[rt][ks], bfr[ct][ks], acc[rt][ct], 0, 0, 0);

        if (ki == 7) {   // fold tile ct8 into running max; re-init acc with next bias
            #pragma unroll
            for (int ct = 0; ct < 2; ct++) {
                const unsigned code = (unsigned)(ct8 * 256 + w * 64 + ct * 32 + l32);
                const float nb = (ct8 < 7) ? -hcv[ct8 + 1][ct] : 0.0f;
                #pragma unroll
                for (int rt = 0; rt < 2; rt++) {
                    #pragma unroll
                    for (int r = 0; r < 16; r++) {
                        unsigned u = (__float_as_uint(acc[rt][ct][r]) & 0xFFFFF800u) | code;
                        mp[rt][r] = fmaxf(mp[rt][r], __uint_as_float(u));
                        acc[rt][ct][r] = nb;
                    }
                }
            }
        }
        cur ^= 1;
    }

    // ---- cross-lane argmax over the 32 lanes sharing each row ----
    #pragma unroll
    for (int m = 1; m <= 16; m <<= 1)
        #pragma unroll
        for (int rt = 0; rt < 2; rt++)
            #pragma unroll
            for (int r = 0; r < 16; r++)
                mp[rt][r] = fmaxf(mp[rt][r], __shfl_xor(mp[rt][r], m, 64));

    if (l32 == 0) {
        #pragma unroll
        for (int rt = 0; rt < 2; rt++)
            #pragma unroll
            for (int r = 0; r < 16; r++) {
                const int row = rt * 32 + (r & 3) + 8 * (r >> 2) + 4 * h;
                red[row][w] = mp[rt][r];
            }
    }
    __syncthreads();
    if (t < 64) {
        float b0 = fmaxf(fmaxf(red[t][0], red[t][1]), fmaxf(red[t][2], red[t][3]));
        inds[row0 + t] = (int)(__float_as_uint(b0) & 2047u);
    }
}

// ---------------- epilogue: gather code vectors + loss --------------------------
__global__ void gather_loss_kernel(const float* __restrict__ x, const float* __restrict__ cb,
                                   const int* __restrict__ inds, float* __restrict__ out,
                                   float* __restrict__ loss) {
    const int t = threadIdx.x;    // 256 threads cover D
    float lsum = 0.0f;
    #pragma unroll
    for (int r = 0; r < 16; r++) {
        const int row  = blockIdx.x * 16 + r;
        const int code = inds[row];
        const float c  = cb[(size_t)code * DIM + t];
        const float xv = x[(size_t)row * DIM + t];
        out[(size_t)row * DIM + t] = c;
        const float diff = xv - c;
        lsum += diff * diff;
    }
    #pragma unroll
    for (int o = 32; o > 0; o >>= 1) lsum += __shfl_down(lsum, o, 64);
    __shared__ float red[4];
    if ((t & 63) == 0) red[t >> 6] = lsum;
    __syncthreads();
    if (t == 0) {
        const float scale = 1.25f / (float)((size_t)N_ROWS * DIM);  // (beta+1)/(N*D)
        atomicAdd(loss, (red[0] + red[1] + red[2] + red[3]) * scale);
    }
}

extern "C" void kernel_launch(void* const* d_in, const int* in_sizes, int n_in,
                              void* d_out, int out_size, void* d_ws, size_t ws_size,
                              hipStream_t stream) {
    const float* x  = (const float*)d_in[0];
    const float* cb = (const float*)d_in[1];
    float* out  = (float*)d_out;
    float* loss = out + (size_t)N_ROWS * DIM;

    // x_bf16 staged in the front of d_out (16 MB); fully overwritten by gather later.
    ushort_t* xb = (ushort_t*)d_out;

    char* ws = (char*)d_ws;
    ushort_t* cbb    = (ushort_t*)ws;                              // 1 MB
    float*    halfcn = (float*)(ws + (size_t)KCODES * DIM * 2);    // 8 KB
    int*      inds   = (int*)(ws + (size_t)KCODES * DIM * 2 + KCODES * 4);

    prep_x<<<N_ROWS * DIM / 2048, 256, 0, stream>>>(x, xb);
    prep_cb<<<KCODES, 256, 0, stream>>>(cb, cbb, halfcn, loss);
    argmin_mfma<<<N_ROWS / 64, 256, 0, stream>>>(xb, cbb, halfcn, inds);
    gather_loss_kernel<<<N_ROWS / 16, 256, 0, stream>>>(x, cb, inds, out, loss);
}